// Round 3
// baseline (392.826 us; speedup 1.0000x reference)
//
#include <hip/hip_runtime.h>

// PortfolioGenerator: B=16384 rows of S=2048 fp32 scores.
// long = scatter(softmax(top256)), short = scatter(softmax(1-bottom256))
//      = softmax(-bottom256) by shift invariance; plus clipped short_ratio.
//
// R3: two-kernel split.
//  k1 select_kernel: one wave/row, exact rank-256 cutoffs via value-binned
//     histogram (bins of 1/64 over [-2,2]) + exact (value,index) ranking of
//     the boundary bin (jax top_k tie stability). Emits 8 floats/row to ws:
//     cutVw, cutIw, cutVl, cutIl, vmax, vmin, 1/Zw, 1/Zl.
//  k2 write_kernel: pure streaming map, no LDS, no barriers: per element one
//     arg-selected exp + predicates; writes both dense outputs. Memory-bound.

#define NT   256
#define WPB  4      // waves (=rows) per block
#define SDIM 2048
#define KSEL 256u
#define EPL  32     // elements per lane (2048 / 64)
#define CAP  128    // boundary-bin candidate capacity (expected ~7)

__device__ __forceinline__ int binOf(float x) {
    int b = (int)__builtin_fmaf(x, 64.f, 128.f);  // width 1/64, covers [-2,2)
    return min(max(b, 0), 255);
}

__global__ void __launch_bounds__(NT) select_kernel(
    const float* __restrict__ scores, float* __restrict__ params) {
    __shared__ unsigned s_hist[WPB][256];
    __shared__ float    s_cW[WPB][CAP];
    __shared__ unsigned s_iW[WPB][CAP];
    __shared__ float    s_cL[WPB][CAP];
    __shared__ unsigned s_iL[WPB][CAP];
    __shared__ unsigned s_nW[WPB], s_nL[WPB];

    const int    lane = threadIdx.x & 63;
    const int    wv   = threadIdx.x >> 6;
    const int    row  = blockIdx.x * WPB + wv;
    const size_t base = (size_t)row * SDIM;

    // ---- load 32 elems/lane; elem (i,c) has idx = i*256 + lane*4 + c ------
    const float4* rp = (const float4*)(scores + base);
    float v[EPL];
#pragma unroll
    for (int i = 0; i < 8; ++i) {
        float4 a     = rp[i * 64 + lane];
        v[4 * i + 0] = a.x;
        v[4 * i + 1] = a.y;
        v[4 * i + 2] = a.z;
        v[4 * i + 3] = a.w;
    }

    // ---- row max/min ------------------------------------------------------
    float vmax = v[0], vmin = v[0];
#pragma unroll
    for (int j = 1; j < EPL; ++j) {
        vmax = fmaxf(vmax, v[j]);
        vmin = fminf(vmin, v[j]);
    }
#pragma unroll
    for (int off = 32; off; off >>= 1) {
        vmax = fmaxf(vmax, __shfl_xor(vmax, off));
        vmin = fminf(vmin, __shfl_xor(vmin, off));
    }

    // ---- per-wave histogram (wave-lockstep; DS ops in-order, no barriers) -
    unsigned* hist = s_hist[wv];
    *((uint4*)&hist[lane * 4]) = make_uint4(0u, 0u, 0u, 0u);
#pragma unroll
    for (int j = 0; j < EPL; ++j) atomicAdd(&hist[binOf(v[j])], 1u);

    // ---- prefix scan over 256 bins (lane owns 4); find boundary bins ------
    uint4    h   = *((const uint4*)&hist[lane * 4]);
    unsigned p0  = h.x, p1 = p0 + h.y, p2 = p1 + h.z, p3 = p2 + h.w;
    unsigned pre = p3;
#pragma unroll
    for (int off = 1; off < 64; off <<= 1) {
        unsigned x = __shfl_up(pre, off);
        if (lane >= off) pre += x;
    }
    const unsigned before = pre - p3;  // elems in bins < 4*lane
    unsigned L[5] = {before, before + p0, before + p1, before + p2, before + p3};
    const unsigned T = (unsigned)SDIM;

    int      bwLoc = -1, blLoc = -1;
    unsigned needwLoc = 0, CwLoc = 0, needlLoc = 0, ClLoc = 0;
#pragma unroll
    for (int c = 0; c < 4; ++c) {
        const unsigned cnt_b = (c == 0) ? h.x : (c == 1) ? h.y : (c == 2) ? h.z : h.w;
        const unsigned tc = T - L[c], tcn = T - L[c + 1];
        if (tc >= KSEL && tcn < KSEL) {          // winner bin (count from top)
            bwLoc    = lane * 4 + c;
            needwLoc = KSEL - tcn;
            CwLoc    = cnt_b;
        }
        if (L[c + 1] >= KSEL && L[c] < KSEL) {   // loser bin (count from bottom)
            blLoc    = lane * 4 + c;
            needlLoc = KSEL - L[c];
            ClLoc    = cnt_b;
        }
    }
    unsigned long long mWb = __ballot(bwLoc >= 0);
    unsigned long long mLb = __ballot(blLoc >= 0);
    const int swl = __ffsll(mWb) - 1, sll = __ffsll(mLb) - 1;
    const int      bw    = __shfl(bwLoc, swl);
    const unsigned needw = (unsigned)__shfl((int)needwLoc, swl);
    const unsigned Cw    = min((unsigned)__shfl((int)CwLoc, swl), (unsigned)CAP);
    const int      bl    = __shfl(blLoc, sll);
    const unsigned needl = (unsigned)__shfl((int)needlLoc, sll);
    const unsigned Cl    = min((unsigned)__shfl((int)ClLoc, sll), (unsigned)CAP);

    // ---- gather both boundary bins in one pass ----------------------------
    if (lane == 0) { s_nW[wv] = 0; s_nL[wv] = 0; }
#pragma unroll
    for (int j = 0; j < EPL; ++j) {
        const int      b   = binOf(v[j]);
        const unsigned idx = (unsigned)((j >> 2) * 256 + lane * 4 + (j & 3));
        if (b == bw) {
            unsigned p = atomicAdd(&s_nW[wv], 1u);
            if (p < CAP) { s_cW[wv][p] = v[j]; s_iW[wv][p] = idx; }
        }
        if (b == bl) {
            unsigned p = atomicAdd(&s_nL[wv], 1u);
            if (p < CAP) { s_cL[wv][p] = v[j]; s_iL[wv][p] = idx; }
        }
    }

    // ---- exact rank within winner bin: find (value,index) of rank needw ---
    float fV = 0.f; unsigned fI = 0; bool found = false;
    for (unsigned c = (unsigned)lane; c < Cw; c += 64) {
        const float    pv = s_cW[wv][c];
        const unsigned pi = s_iW[wv][c];
        unsigned       r  = 0;
        for (unsigned c2 = 0; c2 < Cw; ++c2) {
            const float    qv = s_cW[wv][c2];
            const unsigned qi = s_iW[wv][c2];
            r += (qv > pv) || (qv == pv && qi < pi);
        }
        if (r == needw - 1) { found = true; fV = pv; fI = pi; }
    }
    unsigned long long fm = __ballot(found);
    float    cutVw = INFINITY;
    unsigned cutIw = 0;
    if (fm) {
        const int fl = __ffsll(fm) - 1;
        cutVw = __shfl(fV, fl);
        cutIw = (unsigned)__shfl((int)fI, fl);
    }

    // ---- exact rank within loser bin --------------------------------------
    fV = 0.f; fI = 0; found = false;
    for (unsigned c = (unsigned)lane; c < Cl; c += 64) {
        const float    pv = s_cL[wv][c];
        const unsigned pi = s_iL[wv][c];
        unsigned       r  = 0;
        for (unsigned c2 = 0; c2 < Cl; ++c2) {
            const float    qv = s_cL[wv][c2];
            const unsigned qi = s_iL[wv][c2];
            r += (qv < pv) || (qv == pv && qi < pi);
        }
        if (r == needl - 1) { found = true; fV = pv; fI = pi; }
    }
    fm = __ballot(found);
    float    cutVl = -INFINITY;
    unsigned cutIl = 0;
    if (fm) {
        const int fl = __ffsll(fm) - 1;
        cutVl = __shfl(fV, fl);
        cutIl = (unsigned)__shfl((int)fI, fl);
    }

    // ---- softmax denominators (one arg-selected exp per element) ----------
    float sumW = 0.f, sumL = 0.f;
#pragma unroll
    for (int j = 0; j < EPL; ++j) {
        const unsigned idx  = (unsigned)((j >> 2) * 256 + lane * 4 + (j & 3));
        const bool     selw = (v[j] > cutVw) || (v[j] == cutVw && idx <= cutIw);
        const bool     sell = (v[j] < cutVl) || (v[j] == cutVl && idx <= cutIl);
        const float    e    = __expf(selw ? (v[j] - vmax) : (vmin - v[j]));
        if (selw) sumW += e;
        if (sell) sumL += e;
    }
#pragma unroll
    for (int off = 32; off; off >>= 1) {
        sumW += __shfl_xor(sumW, off);
        sumL += __shfl_xor(sumL, off);
    }

    if (lane == 0) {
        float4* pp = (float4*)(params + (size_t)row * 8);
        pp[0] = make_float4(cutVw, __uint_as_float(cutIw), cutVl,
                            __uint_as_float(cutIl));
        pp[1] = make_float4(vmax, vmin, 1.f / sumW, 1.f / sumL);
    }
}

__global__ void __launch_bounds__(NT) write_kernel(
    const float* __restrict__ scores, const float* __restrict__ params,
    const float* __restrict__ short_ratio, float* __restrict__ out_long,
    float* __restrict__ out_short, float* __restrict__ out_sr) {
    const int    lane = threadIdx.x & 63;
    const int    wv   = threadIdx.x >> 6;
    const int    row  = blockIdx.x * WPB + wv;
    const size_t base = (size_t)row * SDIM;

    const float4 q0 = ((const float4*)params)[row * 2];      // broadcast load
    const float4 q1 = ((const float4*)params)[row * 2 + 1];
    const float    cutVw = q0.x;
    const unsigned cutIw = __float_as_uint(q0.y);
    const float    cutVl = q0.z;
    const unsigned cutIl = __float_as_uint(q0.w);
    const float    vmax = q1.x, vmin = q1.y, izw = q1.z, izl = q1.w;

    const float4* rp = (const float4*)(scores + base);
    float4*       lp = (float4*)(out_long + base);
    float4*       sp = (float4*)(out_short + base);
#pragma unroll
    for (int i = 0; i < 8; ++i) {
        const float4 a     = rp[i * 64 + lane];
        const float  vv[4] = {a.x, a.y, a.z, a.w};
        float        lw[4], sw[4];
#pragma unroll
        for (int c = 0; c < 4; ++c) {
            const unsigned idx  = (unsigned)(i * 256 + lane * 4 + c);
            const bool     selw = (vv[c] > cutVw) || (vv[c] == cutVw && idx <= cutIw);
            const bool     sell = (vv[c] < cutVl) || (vv[c] == cutVl && idx <= cutIl);
            const float    e    = __expf(selw ? (vv[c] - vmax) : (vmin - vv[c]));
            lw[c] = selw ? e * izw : 0.f;
            sw[c] = sell ? e * izl : 0.f;
        }
        lp[i * 64 + lane] = make_float4(lw[0], lw[1], lw[2], lw[3]);
        sp[i * 64 + lane] = make_float4(sw[0], sw[1], sw[2], sw[3]);
    }
    if (lane == 0) out_sr[row] = fminf(fmaxf(short_ratio[row], 0.f), 1.f);
}

extern "C" void kernel_launch(void* const* d_in, const int* in_sizes, int n_in,
                              void* d_out, int out_size, void* d_ws,
                              size_t ws_size, hipStream_t stream) {
    const float* scores = (const float*)d_in[0];
    const float* sr     = (const float*)d_in[1];
    const int    B      = in_sizes[1];  // 16384
    float* out       = (float*)d_out;
    float* out_long  = out;
    float* out_short = out + (size_t)B * SDIM;
    float* out_sr    = out + 2 * (size_t)B * SDIM;
    float* prm       = (float*)d_ws;    // 16384 * 8 floats = 512 KB

    select_kernel<<<B / WPB, NT, 0, stream>>>(scores, prm);
    write_kernel<<<B / WPB, NT, 0, stream>>>(scores, prm, sr, out_long,
                                             out_short, out_sr);
}